// Round 1
// baseline (460.057 us; speedup 1.0000x reference)
//
#include <hip/hip_runtime.h>

#define BS 256

// ---------- dtype detection: is edge_index int64 (flag=1) or int32 (flag=0)? ----------
__global__ void k_detect(const int* __restrict__ idx, int* __restrict__ flag) {
    int l = threadIdx.x;               // 64 threads = 1 wave
    int v = idx[2 * l + 1];            // high words if int64 (values < 2^31 -> all 0)
    unsigned long long b = __ballot(v != 0);
    if (l == 0) flag[0] = (b == 0ULL) ? 1 : 0;
}

__global__ void k_zero(int* __restrict__ p, int n) {
    int i = blockIdx.x * BS + threadIdx.x;
    if (i < n) p[i] = 0;
}

// ---------- degree count over dst ----------
__global__ void k_degree(const int* __restrict__ idx, const int* __restrict__ flag,
                         int* __restrict__ deg, int E) {
    int e = blockIdx.x * BS + threadIdx.x;
    if (e >= E) return;
    int is64 = flag[0];
    long dpos = is64 ? (2L * E + 2L * e) : ((long)E + e);
    int d = idx[dpos];
    atomicAdd(&deg[d], 1);
}

// ---------- exclusive scan: per-chunk (1024 elems / block of 256) ----------
__global__ void k_scan1(const int* __restrict__ deg, int* __restrict__ ptr,
                        int* __restrict__ partials, int n) {
    __shared__ int sd[BS];
    int tid = threadIdx.x;
    int base = blockIdx.x * 1024 + tid * 4;
    int v0 = (base + 0 < n) ? deg[base + 0] : 0;
    int v1 = (base + 1 < n) ? deg[base + 1] : 0;
    int v2 = (base + 2 < n) ? deg[base + 2] : 0;
    int v3 = (base + 3 < n) ? deg[base + 3] : 0;
    int tsum = v0 + v1 + v2 + v3;
    sd[tid] = tsum;
    __syncthreads();
    for (int off = 1; off < BS; off <<= 1) {
        int x = (tid >= off) ? sd[tid - off] : 0;
        __syncthreads();
        sd[tid] += x;
        __syncthreads();
    }
    int run = sd[tid] - tsum;   // exclusive offset within chunk
    if (base + 0 < n) ptr[base + 0] = run; run += v0;
    if (base + 1 < n) ptr[base + 1] = run; run += v1;
    if (base + 2 < n) ptr[base + 2] = run; run += v2;
    if (base + 3 < n) ptr[base + 3] = run;
    if (tid == BS - 1) partials[blockIdx.x] = sd[tid];
}

// ---------- scan the block partials (<=1024 of them) ----------
__global__ void k_scan2(int* __restrict__ partials, int nb) {
    __shared__ int sd[1024];
    int tid = threadIdx.x;
    int orig = (tid < nb) ? partials[tid] : 0;
    sd[tid] = orig;
    __syncthreads();
    for (int off = 1; off < 1024; off <<= 1) {
        int x = (tid >= off) ? sd[tid - off] : 0;
        __syncthreads();
        sd[tid] += x;
        __syncthreads();
    }
    if (tid < nb) partials[tid] = sd[tid] - orig;  // exclusive
}

// ---------- add partial offsets; init cursor; write ptr[n] ----------
__global__ void k_scan3(int* __restrict__ ptr, const int* __restrict__ partials,
                        int* __restrict__ cursor, int n, int E) {
    int i = blockIdx.x * BS + threadIdx.x;
    if (i >= n) return;
    int p = ptr[i] + partials[i >> 10];
    ptr[i] = p;
    cursor[i] = p;
    if (i == 0) ptr[n] = E;
}

// ---------- scatter src indices into CSR buckets ----------
__global__ void k_scatter(const int* __restrict__ idx, const int* __restrict__ flag,
                          int* __restrict__ cursor, int* __restrict__ csr, int E) {
    int e = blockIdx.x * BS + threadIdx.x;
    if (e >= E) return;
    int is64 = flag[0];
    long spos = is64 ? 2L * e : (long)e;
    long dpos = is64 ? (2L * E + 2L * e) : ((long)E + e);
    int s = idx[spos];
    int d = idx[dpos];
    int pos = atomicAdd(&cursor[d], 1);
    csr[pos] = s;
}

// ---------- layer-1 mean aggregation: 16 lanes/node, float4 per lane ----------
__global__ __launch_bounds__(256) void k_agg(const float* __restrict__ x,
                                             const int* __restrict__ ptr,
                                             const int* __restrict__ csr,
                                             float* __restrict__ agg, int n) {
    int node = blockIdx.x * 16 + (threadIdx.x >> 4);
    int lane = threadIdx.x & 15;
    if (node >= n) return;
    int p0 = ptr[node], p1 = ptr[node + 1];
    float ax = 0.f, ay = 0.f, az = 0.f, aw = 0.f;
    for (int e = p0; e < p1; e++) {
        int j = csr[e];
        const float4 v = *(const float4*)(x + (size_t)j * 64 + lane * 4);
        ax += v.x; ay += v.y; az += v.z; aw += v.w;
    }
    int d = p1 - p0; if (d < 1) d = 1;
    float inv = 1.0f / (float)d;
    float4 o = make_float4(ax * inv, ay * inv, az * inv, aw * inv);
    *(float4*)(agg + (size_t)node * 64 + lane * 4) = o;
}

// ---------- fused layer-1 GEMM + relu + layer-2 projections (s,t per node) ----------
__global__ __launch_bounds__(256) void k_gemm(const float* __restrict__ agg,
                                              const float* __restrict__ x,
                                              const float* __restrict__ W1l,
                                              const float* __restrict__ b1,
                                              const float* __restrict__ W1r,
                                              const float* __restrict__ W2l,
                                              const float* __restrict__ W2r,
                                              float* __restrict__ sarr,
                                              float* __restrict__ tarr, int n) {
    int i = blockIdx.x * BS + threadIdx.x;
    if (i >= n) return;
    float acc[64];
#pragma unroll
    for (int j = 0; j < 64; j++) acc[j] = 0.f;
    const float4* arow = (const float4*)(agg + (size_t)i * 64);
    const float4* xrow = (const float4*)(x + (size_t)i * 64);
    for (int k4 = 0; k4 < 16; k4++) {
        float4 a4 = arow[k4];
        float4 x4 = xrow[k4];
#pragma unroll
        for (int kk = 0; kk < 4; kk++) {
            int k = 4 * k4 + kk;
            float av = (kk == 0) ? a4.x : (kk == 1) ? a4.y : (kk == 2) ? a4.z : a4.w;
            float xv = (kk == 0) ? x4.x : (kk == 1) ? x4.y : (kk == 2) ? x4.z : x4.w;
#pragma unroll
            for (int j = 0; j < 64; j++) {
                acc[j] = fmaf(av, W1l[k * 64 + j], fmaf(xv, W1r[k * 64 + j], acc[j]));
            }
        }
    }
    float s = 0.f, t = 0.f;
#pragma unroll
    for (int j = 0; j < 64; j++) {
        float h = acc[j] + b1[j];
        h = fmaxf(h, 0.f);
        s = fmaf(h, W2l[j], s);
        t = fmaf(h, W2r[j], t);
    }
    sarr[i] = s;
    tarr[i] = t;
}

// ---------- layer-2 mean aggregation of scalar s + output ----------
__global__ void k_final(const int* __restrict__ ptr, const int* __restrict__ csr,
                        const float* __restrict__ sarr, const float* __restrict__ tarr,
                        const float* __restrict__ b2, float* __restrict__ out, int n) {
    int i = blockIdx.x * BS + threadIdx.x;
    if (i >= n) return;
    int p0 = ptr[i], p1 = ptr[i + 1];
    float a = 0.f;
    for (int e = p0; e < p1; e++) a += sarr[csr[e]];
    int d = p1 - p0; if (d < 1) d = 1;
    out[i] = a / (float)d + b2[0] + tarr[i];
}

extern "C" void kernel_launch(void* const* d_in, const int* in_sizes, int n_in,
                              void* d_out, int out_size, void* d_ws, size_t ws_size,
                              hipStream_t stream) {
    const float* x   = (const float*)d_in[0];
    const int*   idx = (const int*)d_in[1];
    const float* W1l = (const float*)d_in[2];
    const float* b1  = (const float*)d_in[3];
    const float* W1r = (const float*)d_in[4];
    const float* W2l = (const float*)d_in[5];
    const float* b2  = (const float*)d_in[6];
    const float* W2r = (const float*)d_in[7];
    float* out = (float*)d_out;

    const int n = in_sizes[0] / 64;     // 100000
    const int E = in_sizes[1] / 2;      // 1600000

    // workspace carve-up (256B aligned)
    char* ws = (char*)d_ws;
    size_t off = 0;
    auto carve = [&](size_t bytes) {
        void* p = ws + off;
        off = (off + bytes + 255) & ~(size_t)255;
        return p;
    };
    int*   flag     = (int*)  carve(4);
    int*   deg      = (int*)  carve((size_t)n * 4);
    int*   ptr      = (int*)  carve((size_t)(n + 1) * 4);
    int*   cursor   = (int*)  carve((size_t)n * 4);
    int*   csr      = (int*)  carve((size_t)E * 4);
    int*   partials = (int*)  carve(1024 * 4);
    float* sarr     = (float*)carve((size_t)n * 4);
    float* tarr     = (float*)carve((size_t)n * 4);
    float* agg      = (float*)carve((size_t)n * 64 * 4);
    (void)ws_size; (void)n_in; (void)out_size;

    const int nbN = (n + BS - 1) / BS;
    const int nbE = (E + BS - 1) / BS;
    const int nb1 = (n + 1023) / 1024;   // scan chunks (<=1024 supported)

    k_detect<<<1, 64, 0, stream>>>(idx, flag);
    k_zero<<<nbN, BS, 0, stream>>>(deg, n);
    k_degree<<<nbE, BS, 0, stream>>>(idx, flag, deg, E);
    k_scan1<<<nb1, BS, 0, stream>>>(deg, ptr, partials, n);
    k_scan2<<<1, 1024, 0, stream>>>(partials, nb1);
    k_scan3<<<nbN, BS, 0, stream>>>(ptr, partials, cursor, n, E);
    k_scatter<<<nbE, BS, 0, stream>>>(idx, flag, cursor, csr, E);
    k_agg<<<(n + 15) / 16, BS, 0, stream>>>(x, ptr, csr, agg, n);
    k_gemm<<<nbN, BS, 0, stream>>>(agg, x, W1l, b1, W1r, W2l, W2r, sarr, tarr, n);
    k_final<<<nbN, BS, 0, stream>>>(ptr, csr, sarr, tarr, b2, out, n);
}

// Round 2
// 412.573 us; speedup vs baseline: 1.1151x; 1.1151x over previous
//
#include <hip/hip_runtime.h>

#define BS 256
#define KPASS 4

// ---------- dtype detection: is edge_index int64 (flag=1) or int32 (flag=0)? ----------
__global__ void k_detect(const int* __restrict__ idx, int* __restrict__ flag) {
    int l = threadIdx.x;               // 64 threads = 1 wave
    int v = idx[2 * l + 1];            // high words if int64 (values < 2^31 -> all 0)
    unsigned long long b = __ballot(v != 0);
    if (l == 0) flag[0] = (b == 0ULL) ? 1 : 0;
}

__global__ void k_zero(int* __restrict__ p, int n) {
    int i = blockIdx.x * BS + threadIdx.x;
    if (i < n) p[i] = 0;
}

// ---------- compact int64->int32, count degrees. 4 edges per thread ----------
__global__ void k_prep(const int* __restrict__ idx, const int* __restrict__ flag,
                       int* __restrict__ src32, int* __restrict__ dst32,
                       int* __restrict__ deg, int E) {
    int t = blockIdx.x * BS + threadIdx.x;
    int base = t * 4;
    if (base >= E) return;
    int is64 = flag[0];
    int s[4], d[4];
    if (is64) {
        // src section: int64 at [0,E), dst section: int64 at [E,2E)
        const int4* p_s = (const int4*)(idx + 2L * base);
        const int4* p_d = (const int4*)(idx + 2L * E + 2L * base);
        int4 s0 = p_s[0], s1 = p_s[1];
        int4 d0 = p_d[0], d1 = p_d[1];
        s[0] = s0.x; s[1] = s0.z; s[2] = s1.x; s[3] = s1.z;
        d[0] = d0.x; d[1] = d0.z; d[2] = d1.x; d[3] = d1.z;
    } else {
        const int4 s0 = *(const int4*)(idx + base);
        const int4 d0 = *(const int4*)(idx + (long)E + base);
        s[0] = s0.x; s[1] = s0.y; s[2] = s0.z; s[3] = s0.w;
        d[0] = d0.x; d[1] = d0.y; d[2] = d0.z; d[3] = d0.w;
    }
    int nv = E - base; if (nv > 4) nv = 4;
    if (nv == 4) {
        *(int4*)(src32 + base) = make_int4(s[0], s[1], s[2], s[3]);
        *(int4*)(dst32 + base) = make_int4(d[0], d[1], d[2], d[3]);
        atomicAdd(&deg[d[0]], 1);
        atomicAdd(&deg[d[1]], 1);
        atomicAdd(&deg[d[2]], 1);
        atomicAdd(&deg[d[3]], 1);
    } else {
        for (int j = 0; j < nv; j++) {
            src32[base + j] = s[j];
            dst32[base + j] = d[j];
            atomicAdd(&deg[d[j]], 1);
        }
    }
}

// ---------- exclusive scan: per-chunk (1024 elems / block of 256) ----------
__global__ void k_scan1(const int* __restrict__ deg, int* __restrict__ ptr,
                        int* __restrict__ partials, int n) {
    __shared__ int sd[BS];
    int tid = threadIdx.x;
    int base = blockIdx.x * 1024 + tid * 4;
    int v0 = (base + 0 < n) ? deg[base + 0] : 0;
    int v1 = (base + 1 < n) ? deg[base + 1] : 0;
    int v2 = (base + 2 < n) ? deg[base + 2] : 0;
    int v3 = (base + 3 < n) ? deg[base + 3] : 0;
    int tsum = v0 + v1 + v2 + v3;
    sd[tid] = tsum;
    __syncthreads();
    for (int off = 1; off < BS; off <<= 1) {
        int x = (tid >= off) ? sd[tid - off] : 0;
        __syncthreads();
        sd[tid] += x;
        __syncthreads();
    }
    int run = sd[tid] - tsum;   // exclusive offset within chunk
    if (base + 0 < n) ptr[base + 0] = run; run += v0;
    if (base + 1 < n) ptr[base + 1] = run; run += v1;
    if (base + 2 < n) ptr[base + 2] = run; run += v2;
    if (base + 3 < n) ptr[base + 3] = run;
    if (tid == BS - 1) partials[blockIdx.x] = sd[tid];
}

// ---------- scan the block partials (<=1024 of them) ----------
__global__ void k_scan2(int* __restrict__ partials, int nb) {
    __shared__ int sd[1024];
    int tid = threadIdx.x;
    int orig = (tid < nb) ? partials[tid] : 0;
    sd[tid] = orig;
    __syncthreads();
    for (int off = 1; off < 1024; off <<= 1) {
        int x = (tid >= off) ? sd[tid - off] : 0;
        __syncthreads();
        sd[tid] += x;
        __syncthreads();
    }
    if (tid < nb) partials[tid] = sd[tid] - orig;  // exclusive
}

// ---------- add partial offsets; init cursor; write ptr[n] ----------
__global__ void k_scan3(int* __restrict__ ptr, const int* __restrict__ partials,
                        int* __restrict__ cursor, int n, int E) {
    int i = blockIdx.x * BS + threadIdx.x;
    if (i >= n) return;
    int p = ptr[i] + partials[i >> 10];
    ptr[i] = p;
    cursor[i] = p;
    if (i == 0) ptr[n] = E;
}

// ---------- range-filtered scatter: only dst in [lo,hi) -> L2-local csr writes ----------
__global__ void k_scatter_pass(const int* __restrict__ src32, const int* __restrict__ dst32,
                               int* __restrict__ cursor, int* __restrict__ csr,
                               int E, int lo, int hi) {
    int t = blockIdx.x * BS + threadIdx.x;
    int base = t * 4;
    if (base >= E) return;
    if (base + 4 <= E) {
        int4 d4 = *(const int4*)(dst32 + base);
        int d[4] = {d4.x, d4.y, d4.z, d4.w};
#pragma unroll
        for (int j = 0; j < 4; j++) {
            if (d[j] >= lo && d[j] < hi) {
                int s = src32[base + j];
                int pos = atomicAdd(&cursor[d[j]], 1);
                csr[pos] = s;
            }
        }
    } else {
        for (int j = 0; base + j < E; j++) {
            int d = dst32[base + j];
            if (d >= lo && d < hi) {
                int s = src32[base + j];
                int pos = atomicAdd(&cursor[d], 1);
                csr[pos] = s;
            }
        }
    }
}

// ---------- layer-1 mean aggregation: 16 lanes/node, float4 per lane ----------
__global__ __launch_bounds__(256) void k_agg(const float* __restrict__ x,
                                             const int* __restrict__ ptr,
                                             const int* __restrict__ csr,
                                             float* __restrict__ agg, int n) {
    int node = blockIdx.x * 16 + (threadIdx.x >> 4);
    int lane = threadIdx.x & 15;
    if (node >= n) return;
    int p0 = ptr[node], p1 = ptr[node + 1];
    float ax = 0.f, ay = 0.f, az = 0.f, aw = 0.f;
    for (int e = p0; e < p1; e++) {
        int j = csr[e];
        const float4 v = *(const float4*)(x + (size_t)j * 64 + lane * 4);
        ax += v.x; ay += v.y; az += v.z; aw += v.w;
    }
    int d = p1 - p0; if (d < 1) d = 1;
    float inv = 1.0f / (float)d;
    float4 o = make_float4(ax * inv, ay * inv, az * inv, aw * inv);
    *(float4*)(agg + (size_t)node * 64 + lane * 4) = o;
}

// ---------- fused layer-1 GEMM + relu + layer-2 projections (s,t per node) ----------
__global__ __launch_bounds__(256) void k_gemm(const float* __restrict__ agg,
                                              const float* __restrict__ x,
                                              const float* __restrict__ W1l,
                                              const float* __restrict__ b1,
                                              const float* __restrict__ W1r,
                                              const float* __restrict__ W2l,
                                              const float* __restrict__ W2r,
                                              float* __restrict__ sarr,
                                              float* __restrict__ tarr, int n) {
    int i = blockIdx.x * BS + threadIdx.x;
    if (i >= n) return;
    float acc[64];
#pragma unroll
    for (int j = 0; j < 64; j++) acc[j] = 0.f;
    const float4* arow = (const float4*)(agg + (size_t)i * 64);
    const float4* xrow = (const float4*)(x + (size_t)i * 64);
    for (int k4 = 0; k4 < 16; k4++) {
        float4 a4 = arow[k4];
        float4 x4 = xrow[k4];
#pragma unroll
        for (int kk = 0; kk < 4; kk++) {
            int k = 4 * k4 + kk;
            float av = (kk == 0) ? a4.x : (kk == 1) ? a4.y : (kk == 2) ? a4.z : a4.w;
            float xv = (kk == 0) ? x4.x : (kk == 1) ? x4.y : (kk == 2) ? x4.z : x4.w;
#pragma unroll
            for (int j = 0; j < 64; j++) {
                acc[j] = fmaf(av, W1l[k * 64 + j], fmaf(xv, W1r[k * 64 + j], acc[j]));
            }
        }
    }
    float s = 0.f, t = 0.f;
#pragma unroll
    for (int j = 0; j < 64; j++) {
        float h = acc[j] + b1[j];
        h = fmaxf(h, 0.f);
        s = fmaf(h, W2l[j], s);
        t = fmaf(h, W2r[j], t);
    }
    sarr[i] = s;
    tarr[i] = t;
}

// ---------- layer-2 mean aggregation of scalar s + output ----------
__global__ void k_final(const int* __restrict__ ptr, const int* __restrict__ csr,
                        const float* __restrict__ sarr, const float* __restrict__ tarr,
                        const float* __restrict__ b2, float* __restrict__ out, int n) {
    int i = blockIdx.x * BS + threadIdx.x;
    if (i >= n) return;
    int p0 = ptr[i], p1 = ptr[i + 1];
    float a = 0.f;
    for (int e = p0; e < p1; e++) a += sarr[csr[e]];
    int d = p1 - p0; if (d < 1) d = 1;
    out[i] = a / (float)d + b2[0] + tarr[i];
}

extern "C" void kernel_launch(void* const* d_in, const int* in_sizes, int n_in,
                              void* d_out, int out_size, void* d_ws, size_t ws_size,
                              hipStream_t stream) {
    const float* x   = (const float*)d_in[0];
    const int*   idx = (const int*)d_in[1];
    const float* W1l = (const float*)d_in[2];
    const float* b1  = (const float*)d_in[3];
    const float* W1r = (const float*)d_in[4];
    const float* W2l = (const float*)d_in[5];
    const float* b2  = (const float*)d_in[6];
    const float* W2r = (const float*)d_in[7];
    float* out = (float*)d_out;

    const int n = in_sizes[0] / 64;     // 100000
    const int E = in_sizes[1] / 2;      // 1600000

    // workspace carve-up (256B aligned)
    char* ws = (char*)d_ws;
    size_t off = 0;
    auto carve = [&](size_t bytes) {
        void* p = ws + off;
        off = (off + bytes + 255) & ~(size_t)255;
        return p;
    };
    int*   flag     = (int*)  carve(4);
    int*   deg      = (int*)  carve((size_t)n * 4);
    int*   ptr      = (int*)  carve((size_t)(n + 1) * 4);
    int*   cursor   = (int*)  carve((size_t)n * 4);
    int*   csr      = (int*)  carve((size_t)E * 4);
    int*   partials = (int*)  carve(1024 * 4);
    float* sarr     = (float*)carve((size_t)n * 4);
    float* tarr     = (float*)carve((size_t)n * 4);
    // union region: src32/dst32 (scatter phase) alias agg (agg/gemm phase)
    char*  uni      = (char*) carve((size_t)n * 64 * 4);   // 25.6 MB >= 12.8 MB
    int*   src32    = (int*)  uni;
    int*   dst32    = (int*)  (uni + ((size_t)E * 4 + 255 & ~(size_t)255));
    float* agg      = (float*)uni;
    (void)ws_size; (void)n_in; (void)out_size;

    const int nbN = (n + BS - 1) / BS;
    const int nbE4 = (E / 4 + BS - 1) / BS;   // 4 edges per thread
    const int nb1 = (n + 1023) / 1024;        // scan chunks (<=1024 supported)

    k_detect<<<1, 64, 0, stream>>>(idx, flag);
    k_zero<<<nbN, BS, 0, stream>>>(deg, n);
    k_prep<<<nbE4, BS, 0, stream>>>(idx, flag, src32, dst32, deg, E);
    k_scan1<<<nb1, BS, 0, stream>>>(deg, ptr, partials, n);
    k_scan2<<<1, 1024, 0, stream>>>(partials, nb1);
    k_scan3<<<nbN, BS, 0, stream>>>(ptr, partials, cursor, n, E);
    for (int p = 0; p < KPASS; p++) {
        int lo = (int)((long)n * p / KPASS);
        int hi = (int)((long)n * (p + 1) / KPASS);
        k_scatter_pass<<<nbE4, BS, 0, stream>>>(src32, dst32, cursor, csr, E, lo, hi);
    }
    k_agg<<<(n + 15) / 16, BS, 0, stream>>>(x, ptr, csr, agg, n);
    k_gemm<<<nbN, BS, 0, stream>>>(agg, x, W1l, b1, W1r, W2l, W2r, sarr, tarr, n);
    k_final<<<nbN, BS, 0, stream>>>(ptr, csr, sarr, tarr, b2, out, n);
}

// Round 3
// 407.291 us; speedup vs baseline: 1.1296x; 1.0130x over previous
//
#include <hip/hip_runtime.h>

#define BS 256
#define KPASS 4
#define NPB 64            // nodes per fused block
#define XS_STRIDE 68      // 64 + 4 pad: breaks 4-way bank alias on scalar reads

// ---------- dtype detection: is edge_index int64 (flag=1) or int32 (flag=0)? ----------
__global__ void k_detect(const int* __restrict__ idx, int* __restrict__ flag) {
    int l = threadIdx.x;               // 64 threads = 1 wave
    int v = idx[2 * l + 1];            // high words if int64 (values < 2^31 -> all 0)
    unsigned long long b = __ballot(v != 0);
    if (l == 0) flag[0] = (b == 0ULL) ? 1 : 0;
}

__global__ void k_zero(int* __restrict__ p, int n) {
    int i = blockIdx.x * BS + threadIdx.x;
    if (i < n) p[i] = 0;
}

// ---------- compact int64->int32, count degrees. 4 edges per thread ----------
__global__ void k_prep(const int* __restrict__ idx, const int* __restrict__ flag,
                       int* __restrict__ src32, int* __restrict__ dst32,
                       int* __restrict__ deg, int E) {
    int t = blockIdx.x * BS + threadIdx.x;
    int base = t * 4;
    if (base >= E) return;
    int is64 = flag[0];
    int s[4], d[4];
    if (is64) {
        const int4* p_s = (const int4*)(idx + 2L * base);
        const int4* p_d = (const int4*)(idx + 2L * E + 2L * base);
        int4 s0 = p_s[0], s1 = p_s[1];
        int4 d0 = p_d[0], d1 = p_d[1];
        s[0] = s0.x; s[1] = s0.z; s[2] = s1.x; s[3] = s1.z;
        d[0] = d0.x; d[1] = d0.z; d[2] = d1.x; d[3] = d1.z;
    } else {
        const int4 s0 = *(const int4*)(idx + base);
        const int4 d0 = *(const int4*)(idx + (long)E + base);
        s[0] = s0.x; s[1] = s0.y; s[2] = s0.z; s[3] = s0.w;
        d[0] = d0.x; d[1] = d0.y; d[2] = d0.z; d[3] = d0.w;
    }
    int nv = E - base; if (nv > 4) nv = 4;
    if (nv == 4) {
        *(int4*)(src32 + base) = make_int4(s[0], s[1], s[2], s[3]);
        *(int4*)(dst32 + base) = make_int4(d[0], d[1], d[2], d[3]);
        atomicAdd(&deg[d[0]], 1);
        atomicAdd(&deg[d[1]], 1);
        atomicAdd(&deg[d[2]], 1);
        atomicAdd(&deg[d[3]], 1);
    } else {
        for (int j = 0; j < nv; j++) {
            src32[base + j] = s[j];
            dst32[base + j] = d[j];
            atomicAdd(&deg[d[j]], 1);
        }
    }
}

// ---------- exclusive scan: per-chunk (1024 elems / block of 256) ----------
__global__ void k_scan1(const int* __restrict__ deg, int* __restrict__ ptr,
                        int* __restrict__ partials, int n) {
    __shared__ int sd[BS];
    int tid = threadIdx.x;
    int base = blockIdx.x * 1024 + tid * 4;
    int v0 = (base + 0 < n) ? deg[base + 0] : 0;
    int v1 = (base + 1 < n) ? deg[base + 1] : 0;
    int v2 = (base + 2 < n) ? deg[base + 2] : 0;
    int v3 = (base + 3 < n) ? deg[base + 3] : 0;
    int tsum = v0 + v1 + v2 + v3;
    sd[tid] = tsum;
    __syncthreads();
    for (int off = 1; off < BS; off <<= 1) {
        int x = (tid >= off) ? sd[tid - off] : 0;
        __syncthreads();
        sd[tid] += x;
        __syncthreads();
    }
    int run = sd[tid] - tsum;   // exclusive offset within chunk
    if (base + 0 < n) ptr[base + 0] = run; run += v0;
    if (base + 1 < n) ptr[base + 1] = run; run += v1;
    if (base + 2 < n) ptr[base + 2] = run; run += v2;
    if (base + 3 < n) ptr[base + 3] = run;
    if (tid == BS - 1) partials[blockIdx.x] = sd[tid];
}

// ---------- scan the block partials (<=1024 of them) ----------
__global__ void k_scan2(int* __restrict__ partials, int nb) {
    __shared__ int sd[1024];
    int tid = threadIdx.x;
    int orig = (tid < nb) ? partials[tid] : 0;
    sd[tid] = orig;
    __syncthreads();
    for (int off = 1; off < 1024; off <<= 1) {
        int x = (tid >= off) ? sd[tid - off] : 0;
        __syncthreads();
        sd[tid] += x;
        __syncthreads();
    }
    if (tid < nb) partials[tid] = sd[tid] - orig;  // exclusive
}

// ---------- add partial offsets; init cursor; write ptr[n] ----------
__global__ void k_scan3(int* __restrict__ ptr, const int* __restrict__ partials,
                        int* __restrict__ cursor, int n, int E) {
    int i = blockIdx.x * BS + threadIdx.x;
    if (i >= n) return;
    int p = ptr[i] + partials[i >> 10];
    ptr[i] = p;
    cursor[i] = p;
    if (i == 0) ptr[n] = E;
}

// ---------- range-filtered scatter: only dst in [lo,hi) -> L2-local csr writes ----------
__global__ void k_scatter_pass(const int* __restrict__ src32, const int* __restrict__ dst32,
                               int* __restrict__ cursor, int* __restrict__ csr,
                               int E, int lo, int hi) {
    int t = blockIdx.x * BS + threadIdx.x;
    int base = t * 4;
    if (base >= E) return;
    if (base + 4 <= E) {
        int4 d4 = *(const int4*)(dst32 + base);
        int d[4] = {d4.x, d4.y, d4.z, d4.w};
#pragma unroll
        for (int j = 0; j < 4; j++) {
            if (d[j] >= lo && d[j] < hi) {
                int s = src32[base + j];
                int pos = atomicAdd(&cursor[d[j]], 1);
                csr[pos] = s;
            }
        }
    } else {
        for (int j = 0; base + j < E; j++) {
            int d = dst32[base + j];
            if (d >= lo && d < hi) {
                int s = src32[base + j];
                int pos = atomicAdd(&cursor[d], 1);
                csr[pos] = s;
            }
        }
    }
}

// ---------- FUSED: mean-agg + layer1 GEMM + relu + layer2 projections ----------
// Block = 1024 threads = 64 nodes. Phase 1: 16 lanes/node aggregate into LDS.
// Phase 2: 16 threads/node x 4 outputs, weights in LDS, shfl-reduce s,t.
__global__ __launch_bounds__(1024) void k_agg_gemm(
        const float* __restrict__ x,
        const int* __restrict__ ptr, const int* __restrict__ csr,
        const float* __restrict__ W1l, const float* __restrict__ b1,
        const float* __restrict__ W1r, const float* __restrict__ W2l,
        const float* __restrict__ W2r,
        float* __restrict__ sarr, float* __restrict__ tarr, int n) {
    __shared__ float w1l_s[64 * 64];
    __shared__ float w1r_s[64 * 64];
    __shared__ float x_s[NPB * XS_STRIDE];
    __shared__ float a_s[NPB * XS_STRIDE];
    __shared__ float b1_s[64], w2l_s[64], w2r_s[64];

    int tid = threadIdx.x;
    // stage weights: 4096 floats each, 1024 threads -> one float4 each
    {
        int i = tid * 4;
        *(float4*)(w1l_s + i) = *(const float4*)(W1l + i);
        *(float4*)(w1r_s + i) = *(const float4*)(W1r + i);
        if (tid < 64) { b1_s[tid] = b1[tid]; w2l_s[tid] = W2l[tid]; w2r_s[tid] = W2r[tid]; }
    }

    int nl = tid >> 4;          // node_local 0..63
    int lane = tid & 15;
    int node = blockIdx.x * NPB + nl;

    if (node < n) {
        // stage own x row
        float4 xv = *(const float4*)(x + (size_t)node * 64 + lane * 4);
        *(float4*)(x_s + nl * XS_STRIDE + lane * 4) = xv;
        // aggregate neighbors
        int p0 = ptr[node], p1 = ptr[node + 1];
        float ax = 0.f, ay = 0.f, az = 0.f, aw = 0.f;
        for (int e = p0; e < p1; e++) {
            int j = csr[e];
            const float4 v = *(const float4*)(x + (size_t)j * 64 + lane * 4);
            ax += v.x; ay += v.y; az += v.z; aw += v.w;
        }
        int d = p1 - p0; if (d < 1) d = 1;
        float inv = 1.0f / (float)d;
        *(float4*)(a_s + nl * XS_STRIDE + lane * 4) =
            make_float4(ax * inv, ay * inv, az * inv, aw * inv);
    }
    __syncthreads();
    if (node >= n) return;

    // phase 2: this thread owns outputs [4*lane, 4*lane+4)
    const float* xr = x_s + nl * XS_STRIDE;
    const float* ar = a_s + nl * XS_STRIDE;
    float a0 = 0.f, a1 = 0.f, a2 = 0.f, a3 = 0.f;   // agg @ W1l
    float c0 = 0.f, c1 = 0.f, c2 = 0.f, c3 = 0.f;   // x   @ W1r
#pragma unroll 8
    for (int k = 0; k < 64; k++) {
        float av = ar[k];
        float xv = xr[k];
        float4 wl = *(const float4*)(w1l_s + k * 64 + lane * 4);
        float4 wr = *(const float4*)(w1r_s + k * 64 + lane * 4);
        a0 = fmaf(av, wl.x, a0); a1 = fmaf(av, wl.y, a1);
        a2 = fmaf(av, wl.z, a2); a3 = fmaf(av, wl.w, a3);
        c0 = fmaf(xv, wr.x, c0); c1 = fmaf(xv, wr.y, c1);
        c2 = fmaf(xv, wr.z, c2); c3 = fmaf(xv, wr.w, c3);
    }
    float s = 0.f, t = 0.f;
    int j0 = 4 * lane;
    float h;
    h = fmaxf(a0 + c0 + b1_s[j0 + 0], 0.f); s = fmaf(h, w2l_s[j0 + 0], s); t = fmaf(h, w2r_s[j0 + 0], t);
    h = fmaxf(a1 + c1 + b1_s[j0 + 1], 0.f); s = fmaf(h, w2l_s[j0 + 1], s); t = fmaf(h, w2r_s[j0 + 1], t);
    h = fmaxf(a2 + c2 + b1_s[j0 + 2], 0.f); s = fmaf(h, w2l_s[j0 + 2], s); t = fmaf(h, w2r_s[j0 + 2], t);
    h = fmaxf(a3 + c3 + b1_s[j0 + 3], 0.f); s = fmaf(h, w2l_s[j0 + 3], s); t = fmaf(h, w2r_s[j0 + 3], t);
    // reduce across the 16 lanes of this node group
#pragma unroll
    for (int m = 8; m >= 1; m >>= 1) {
        s += __shfl_xor(s, m, 16);
        t += __shfl_xor(t, m, 16);
    }
    if (lane == 0) { sarr[node] = s; tarr[node] = t; }
}

// ---------- layer-2 mean aggregation of scalar s + output ----------
__global__ void k_final(const int* __restrict__ ptr, const int* __restrict__ csr,
                        const float* __restrict__ sarr, const float* __restrict__ tarr,
                        const float* __restrict__ b2, float* __restrict__ out, int n) {
    int i = blockIdx.x * BS + threadIdx.x;
    if (i >= n) return;
    int p0 = ptr[i], p1 = ptr[i + 1];
    float a = 0.f;
    for (int e = p0; e < p1; e++) a += sarr[csr[e]];
    int d = p1 - p0; if (d < 1) d = 1;
    out[i] = a / (float)d + b2[0] + tarr[i];
}

extern "C" void kernel_launch(void* const* d_in, const int* in_sizes, int n_in,
                              void* d_out, int out_size, void* d_ws, size_t ws_size,
                              hipStream_t stream) {
    const float* x   = (const float*)d_in[0];
    const int*   idx = (const int*)d_in[1];
    const float* W1l = (const float*)d_in[2];
    const float* b1  = (const float*)d_in[3];
    const float* W1r = (const float*)d_in[4];
    const float* W2l = (const float*)d_in[5];
    const float* b2  = (const float*)d_in[6];
    const float* W2r = (const float*)d_in[7];
    float* out = (float*)d_out;

    const int n = in_sizes[0] / 64;     // 100000
    const int E = in_sizes[1] / 2;      // 1600000

    // workspace carve-up (256B aligned)
    char* ws = (char*)d_ws;
    size_t off = 0;
    auto carve = [&](size_t bytes) {
        void* p = ws + off;
        off = (off + bytes + 255) & ~(size_t)255;
        return p;
    };
    int*   flag     = (int*)  carve(4);
    int*   deg      = (int*)  carve((size_t)n * 4);
    int*   ptr      = (int*)  carve((size_t)(n + 1) * 4);
    int*   cursor   = (int*)  carve((size_t)n * 4);
    int*   csr      = (int*)  carve((size_t)E * 4);
    int*   partials = (int*)  carve(1024 * 4);
    float* sarr     = (float*)carve((size_t)n * 4);
    float* tarr     = (float*)carve((size_t)n * 4);
    int*   src32    = (int*)  carve((size_t)E * 4);
    int*   dst32    = (int*)  carve((size_t)E * 4);
    (void)ws_size; (void)n_in; (void)out_size;

    const int nbN = (n + BS - 1) / BS;
    const int nbE4 = (E / 4 + BS - 1) / BS;   // 4 edges per thread
    const int nb1 = (n + 1023) / 1024;        // scan chunks (<=1024 supported)

    k_detect<<<1, 64, 0, stream>>>(idx, flag);
    k_zero<<<nbN, BS, 0, stream>>>(deg, n);
    k_prep<<<nbE4, BS, 0, stream>>>(idx, flag, src32, dst32, deg, E);
    k_scan1<<<nb1, BS, 0, stream>>>(deg, ptr, partials, n);
    k_scan2<<<1, 1024, 0, stream>>>(partials, nb1);
    k_scan3<<<nbN, BS, 0, stream>>>(ptr, partials, cursor, n, E);
    for (int p = 0; p < KPASS; p++) {
        int lo = (int)((long)n * p / KPASS);
        int hi = (int)((long)n * (p + 1) / KPASS);
        k_scatter_pass<<<nbE4, BS, 0, stream>>>(src32, dst32, cursor, csr, E, lo, hi);
    }
    k_agg_gemm<<<(n + NPB - 1) / NPB, 1024, 0, stream>>>(
        x, ptr, csr, W1l, b1, W1r, W2l, W2r, sarr, tarr, n);
    k_final<<<nbN, BS, 0, stream>>>(ptr, csr, sarr, tarr, b2, out, n);
}

// Round 4
// 318.533 us; speedup vs baseline: 1.4443x; 1.2786x over previous
//
#include <hip/hip_runtime.h>

#define BS 256
#define KPASS 4

typedef __attribute__((ext_vector_type(8))) short bf16x8;
typedef __attribute__((ext_vector_type(4))) float f32x4;

__device__ inline unsigned bfpack2(float a, float b) {
    unsigned ua = __float_as_uint(a), ub = __float_as_uint(b);
    ua = (ua + 0x7fffu + ((ua >> 16) & 1u)) >> 16;
    ub = (ub + 0x7fffu + ((ub >> 16) & 1u)) >> 16;
    return ua | (ub << 16);
}
__device__ inline short bf16of(float a) {
    unsigned ua = __float_as_uint(a);
    ua = (ua + 0x7fffu + ((ua >> 16) & 1u)) >> 16;
    return (short)ua;
}
__device__ inline float lo16(unsigned u) { return __uint_as_float(u << 16); }
__device__ inline float hi16(unsigned u) { return __uint_as_float(u & 0xffff0000u); }

// ---------- dtype detection ----------
__global__ void k_detect(const int* __restrict__ idx, int* __restrict__ flag) {
    int l = threadIdx.x;
    int v = idx[2 * l + 1];
    unsigned long long b = __ballot(v != 0);
    if (l == 0) flag[0] = (b == 0ULL) ? 1 : 0;
}

__global__ void k_zero(int* __restrict__ p, int n) {
    int i = blockIdx.x * BS + threadIdx.x;
    if (i < n) p[i] = 0;
}

// ---------- convert x to bf16 rows ----------
__global__ void k_xbf16(const float* __restrict__ x, unsigned* __restrict__ xb, int total8) {
    int i = blockIdx.x * BS + threadIdx.x;   // one per 8 floats
    if (i >= total8) return;
    const float4 a = *(const float4*)(x + (size_t)i * 8);
    const float4 b = *(const float4*)(x + (size_t)i * 8 + 4);
    uint4 o;
    o.x = bfpack2(a.x, a.y); o.y = bfpack2(a.z, a.w);
    o.z = bfpack2(b.x, b.y); o.w = bfpack2(b.z, b.w);
    *(uint4*)(xb + (size_t)i * 4) = o;
}

// ---------- compact int64->int32, count degrees ----------
__global__ void k_prep(const int* __restrict__ idx, const int* __restrict__ flag,
                       int* __restrict__ src32, int* __restrict__ dst32,
                       int* __restrict__ deg, int E) {
    int t = blockIdx.x * BS + threadIdx.x;
    int base = t * 4;
    if (base >= E) return;
    int is64 = flag[0];
    int s[4], d[4];
    if (is64) {
        const int4* p_s = (const int4*)(idx + 2L * base);
        const int4* p_d = (const int4*)(idx + 2L * E + 2L * base);
        int4 s0 = p_s[0], s1 = p_s[1];
        int4 d0 = p_d[0], d1 = p_d[1];
        s[0] = s0.x; s[1] = s0.z; s[2] = s1.x; s[3] = s1.z;
        d[0] = d0.x; d[1] = d0.z; d[2] = d1.x; d[3] = d1.z;
    } else {
        const int4 s0 = *(const int4*)(idx + base);
        const int4 d0 = *(const int4*)(idx + (long)E + base);
        s[0] = s0.x; s[1] = s0.y; s[2] = s0.z; s[3] = s0.w;
        d[0] = d0.x; d[1] = d0.y; d[2] = d0.z; d[3] = d0.w;
    }
    int nv = E - base; if (nv > 4) nv = 4;
    if (nv == 4) {
        *(int4*)(src32 + base) = make_int4(s[0], s[1], s[2], s[3]);
        *(int4*)(dst32 + base) = make_int4(d[0], d[1], d[2], d[3]);
        atomicAdd(&deg[d[0]], 1);
        atomicAdd(&deg[d[1]], 1);
        atomicAdd(&deg[d[2]], 1);
        atomicAdd(&deg[d[3]], 1);
    } else {
        for (int j = 0; j < nv; j++) {
            src32[base + j] = s[j];
            dst32[base + j] = d[j];
            atomicAdd(&deg[d[j]], 1);
        }
    }
}

// ---------- exclusive scan ----------
__global__ void k_scan1(const int* __restrict__ deg, int* __restrict__ ptr,
                        int* __restrict__ partials, int n) {
    __shared__ int sd[BS];
    int tid = threadIdx.x;
    int base = blockIdx.x * 1024 + tid * 4;
    int v0 = (base + 0 < n) ? deg[base + 0] : 0;
    int v1 = (base + 1 < n) ? deg[base + 1] : 0;
    int v2 = (base + 2 < n) ? deg[base + 2] : 0;
    int v3 = (base + 3 < n) ? deg[base + 3] : 0;
    int tsum = v0 + v1 + v2 + v3;
    sd[tid] = tsum;
    __syncthreads();
    for (int off = 1; off < BS; off <<= 1) {
        int x = (tid >= off) ? sd[tid - off] : 0;
        __syncthreads();
        sd[tid] += x;
        __syncthreads();
    }
    int run = sd[tid] - tsum;
    if (base + 0 < n) ptr[base + 0] = run; run += v0;
    if (base + 1 < n) ptr[base + 1] = run; run += v1;
    if (base + 2 < n) ptr[base + 2] = run; run += v2;
    if (base + 3 < n) ptr[base + 3] = run;
    if (tid == BS - 1) partials[blockIdx.x] = sd[tid];
}

__global__ void k_scan2(int* __restrict__ partials, int nb) {
    __shared__ int sd[1024];
    int tid = threadIdx.x;
    int orig = (tid < nb) ? partials[tid] : 0;
    sd[tid] = orig;
    __syncthreads();
    for (int off = 1; off < 1024; off <<= 1) {
        int x = (tid >= off) ? sd[tid - off] : 0;
        __syncthreads();
        sd[tid] += x;
        __syncthreads();
    }
    if (tid < nb) partials[tid] = sd[tid] - orig;
}

__global__ void k_scan3(int* __restrict__ ptr, const int* __restrict__ partials,
                        int* __restrict__ cursor, int n, int E) {
    int i = blockIdx.x * BS + threadIdx.x;
    if (i >= n) return;
    int p = ptr[i] + partials[i >> 10];
    ptr[i] = p;
    cursor[i] = p;
    if (i == 0) ptr[n] = E;
}

// ---------- range-filtered scatter ----------
__global__ void k_scatter_pass(const int* __restrict__ src32, const int* __restrict__ dst32,
                               int* __restrict__ cursor, int* __restrict__ csr,
                               int E, int lo, int hi) {
    int t = blockIdx.x * BS + threadIdx.x;
    int base = t * 4;
    if (base >= E) return;
    if (base + 4 <= E) {
        int4 d4 = *(const int4*)(dst32 + base);
        int d[4] = {d4.x, d4.y, d4.z, d4.w};
#pragma unroll
        for (int j = 0; j < 4; j++) {
            if (d[j] >= lo && d[j] < hi) {
                int s = src32[base + j];
                int pos = atomicAdd(&cursor[d[j]], 1);
                csr[pos] = s;
            }
        }
    } else {
        for (int j = 0; base + j < E; j++) {
            int d = dst32[base + j];
            if (d >= lo && d < hi) {
                int s = src32[base + j];
                int pos = atomicAdd(&cursor[d], 1);
                csr[pos] = s;
            }
        }
    }
}

// ---------- layer-1 mean aggregation over bf16 rows, 4-deep MLP ----------
__global__ __launch_bounds__(256) void k_agg2(const unsigned short* __restrict__ xb,
                                              const int* __restrict__ ptr,
                                              const int* __restrict__ csr,
                                              unsigned short* __restrict__ aggb, int n) {
    int node = blockIdx.x * 16 + (threadIdx.x >> 4);
    int lane = threadIdx.x & 15;
    if (node >= n) return;
    int p0 = ptr[node], p1 = ptr[node + 1];
    float f0 = 0.f, f1 = 0.f, f2 = 0.f, f3 = 0.f;
    const unsigned short* base = xb + lane * 4;
    int e = p0;
    for (; e + 4 <= p1; e += 4) {
        int j0 = csr[e], j1 = csr[e + 1], j2 = csr[e + 2], j3 = csr[e + 3];
        uint2 v0 = *(const uint2*)(base + (size_t)j0 * 64);
        uint2 v1 = *(const uint2*)(base + (size_t)j1 * 64);
        uint2 v2 = *(const uint2*)(base + (size_t)j2 * 64);
        uint2 v3 = *(const uint2*)(base + (size_t)j3 * 64);
        f0 += lo16(v0.x) + lo16(v1.x) + lo16(v2.x) + lo16(v3.x);
        f1 += hi16(v0.x) + hi16(v1.x) + hi16(v2.x) + hi16(v3.x);
        f2 += lo16(v0.y) + lo16(v1.y) + lo16(v2.y) + lo16(v3.y);
        f3 += hi16(v0.y) + hi16(v1.y) + hi16(v2.y) + hi16(v3.y);
    }
    for (; e < p1; e++) {
        int j = csr[e];
        uint2 v = *(const uint2*)(base + (size_t)j * 64);
        f0 += lo16(v.x); f1 += hi16(v.x); f2 += lo16(v.y); f3 += hi16(v.y);
    }
    int d = p1 - p0; if (d < 1) d = 1;
    float inv = 1.0f / (float)d;
    uint2 o;
    o.x = bfpack2(f0 * inv, f1 * inv);
    o.y = bfpack2(f2 * inv, f3 * inv);
    *(uint2*)(aggb + (size_t)node * 64 + lane * 4) = o;
}

// ---------- MFMA layer-1 GEMM + relu + layer-2 projections ----------
// wave = 16 nodes. A-frags straight from bf16 rows (no LDS). B = weights in regs.
__global__ __launch_bounds__(256) void k_gemm_mfma(
        const unsigned short* __restrict__ aggb, const unsigned short* __restrict__ xb,
        const float* __restrict__ W1l, const float* __restrict__ b1,
        const float* __restrict__ W1r, const float* __restrict__ W2l,
        const float* __restrict__ W2r,
        float* __restrict__ sarr, float* __restrict__ tarr, int n, int ntiles) {
    int lane = threadIdx.x & 63;
    int nloc = lane & 15;        // A row m / D col n
    int quad = lane >> 4;
    int wave = blockIdx.x * 4 + (threadIdx.x >> 6);
    int nwaves = gridDim.x * 4;

    // B fragments: [path][jtile][kstep], B[k][n]: k = s*32 + quad*8 + i, n = nloc
    bf16x8 bfrag[2][4][2];
#pragma unroll
    for (int t = 0; t < 4; t++)
#pragma unroll
        for (int s = 0; s < 2; s++)
#pragma unroll
            for (int i = 0; i < 8; i++) {
                int k = s * 32 + quad * 8 + i;
                int j = t * 16 + nloc;
                bfrag[0][t][s][i] = bf16of(W1l[k * 64 + j]);
                bfrag[1][t][s][i] = bf16of(W1r[k * 64 + j]);
            }
    float b1v[4], w2lv[4], w2rv[4];
#pragma unroll
    for (int t = 0; t < 4; t++) {
        b1v[t] = b1[t * 16 + nloc];
        w2lv[t] = W2l[t * 16 + nloc];
        w2rv[t] = W2r[t * 16 + nloc];
    }

    for (int tile = wave; tile < ntiles; tile += nwaves) {
        int node = tile * 16 + nloc;
        int nc = node < n ? node : (n - 1);
        const unsigned short* ar = aggb + (size_t)nc * 64;
        const unsigned short* xr = xb + (size_t)nc * 64;
        bf16x8 aA0 = *(const bf16x8*)(ar + quad * 8);
        bf16x8 aA1 = *(const bf16x8*)(ar + 32 + quad * 8);
        bf16x8 aX0 = *(const bf16x8*)(xr + quad * 8);
        bf16x8 aX1 = *(const bf16x8*)(xr + 32 + quad * 8);
        f32x4 acc[4];
#pragma unroll
        for (int t = 0; t < 4; t++) {
            acc[t] = (f32x4){0.f, 0.f, 0.f, 0.f};
            acc[t] = __builtin_amdgcn_mfma_f32_16x16x32_bf16(aA0, bfrag[0][t][0], acc[t], 0, 0, 0);
            acc[t] = __builtin_amdgcn_mfma_f32_16x16x32_bf16(aA1, bfrag[0][t][1], acc[t], 0, 0, 0);
            acc[t] = __builtin_amdgcn_mfma_f32_16x16x32_bf16(aX0, bfrag[1][t][0], acc[t], 0, 0, 0);
            acc[t] = __builtin_amdgcn_mfma_f32_16x16x32_bf16(aX1, bfrag[1][t][1], acc[t], 0, 0, 0);
        }
        // epilogue: D row = quad*4 + r (node), col = nloc + 16*t (j)
        float sr[4] = {0.f, 0.f, 0.f, 0.f};
        float tr[4] = {0.f, 0.f, 0.f, 0.f};
#pragma unroll
        for (int t = 0; t < 4; t++)
#pragma unroll
            for (int r = 0; r < 4; r++) {
                float h = acc[t][r] + b1v[t];
                h = fmaxf(h, 0.f);
                sr[r] = fmaf(h, w2lv[t], sr[r]);
                tr[r] = fmaf(h, w2rv[t], tr[r]);
            }
#pragma unroll
        for (int m = 1; m < 16; m <<= 1) {
#pragma unroll
            for (int r = 0; r < 4; r++) {
                sr[r] += __shfl_xor(sr[r], m);
                tr[r] += __shfl_xor(tr[r], m);
            }
        }
        if (nloc == 0) {
#pragma unroll
            for (int r = 0; r < 4; r++) {
                int nd = tile * 16 + quad * 4 + r;
                if (nd < n) { sarr[nd] = sr[r]; tarr[nd] = tr[r]; }
            }
        }
    }
}

// ---------- layer-2 mean aggregation of scalar s + output ----------
__global__ void k_final(const int* __restrict__ ptr, const int* __restrict__ csr,
                        const float* __restrict__ sarr, const float* __restrict__ tarr,
                        const float* __restrict__ b2, float* __restrict__ out, int n) {
    int i = blockIdx.x * BS + threadIdx.x;
    if (i >= n) return;
    int p0 = ptr[i], p1 = ptr[i + 1];
    float a = 0.f;
    int e = p0;
    for (; e + 4 <= p1; e += 4) {
        int j0 = csr[e], j1 = csr[e + 1], j2 = csr[e + 2], j3 = csr[e + 3];
        a += sarr[j0] + sarr[j1] + sarr[j2] + sarr[j3];
    }
    for (; e < p1; e++) a += sarr[csr[e]];
    int d = p1 - p0; if (d < 1) d = 1;
    out[i] = a / (float)d + b2[0] + tarr[i];
}

extern "C" void kernel_launch(void* const* d_in, const int* in_sizes, int n_in,
                              void* d_out, int out_size, void* d_ws, size_t ws_size,
                              hipStream_t stream) {
    const float* x   = (const float*)d_in[0];
    const int*   idx = (const int*)d_in[1];
    const float* W1l = (const float*)d_in[2];
    const float* b1  = (const float*)d_in[3];
    const float* W1r = (const float*)d_in[4];
    const float* W2l = (const float*)d_in[5];
    const float* b2  = (const float*)d_in[6];
    const float* W2r = (const float*)d_in[7];
    float* out = (float*)d_out;

    const int n = in_sizes[0] / 64;     // 100000
    const int E = in_sizes[1] / 2;      // 1600000

    char* ws = (char*)d_ws;
    size_t off = 0;
    auto carve = [&](size_t bytes) {
        void* p = ws + off;
        off = (off + bytes + 255) & ~(size_t)255;
        return p;
    };
    int*   flag     = (int*)  carve(4);
    int*   deg      = (int*)  carve((size_t)n * 4);
    int*   ptr      = (int*)  carve((size_t)(n + 1) * 4);
    int*   cursor   = (int*)  carve((size_t)n * 4);
    int*   csr      = (int*)  carve((size_t)E * 4);
    int*   partials = (int*)  carve(1024 * 4);
    float* sarr     = (float*)carve((size_t)n * 4);
    float* tarr     = (float*)carve((size_t)n * 4);
    int*   src32    = (int*)  carve((size_t)E * 4);
    int*   dst32    = (int*)  carve((size_t)E * 4);
    unsigned short* xbu  = (unsigned short*)carve((size_t)n * 64 * 2);
    unsigned short* aggb = (unsigned short*)carve((size_t)n * 64 * 2);
    (void)ws_size; (void)n_in; (void)out_size;

    const int nbN = (n + BS - 1) / BS;
    const int nbE4 = ((E + 3) / 4 + BS - 1) / BS;
    const int nb1 = (n + 1023) / 1024;
    const int total8 = n * 64 / 8;
    const int ntiles = (n + 15) / 16;

    k_detect<<<1, 64, 0, stream>>>(idx, flag);
    k_zero<<<nbN, BS, 0, stream>>>(deg, n);
    k_xbf16<<<(total8 + BS - 1) / BS, BS, 0, stream>>>(x, (unsigned*)xbu, total8);
    k_prep<<<nbE4, BS, 0, stream>>>(idx, flag, src32, dst32, deg, E);
    k_scan1<<<nb1, BS, 0, stream>>>(deg, ptr, partials, n);
    k_scan2<<<1, 1024, 0, stream>>>(partials, nb1);
    k_scan3<<<nbN, BS, 0, stream>>>(ptr, partials, cursor, n, E);
    for (int p = 0; p < KPASS; p++) {
        int lo = (int)((long)n * p / KPASS);
        int hi = (int)((long)n * (p + 1) / KPASS);
        k_scatter_pass<<<nbE4, BS, 0, stream>>>(src32, dst32, cursor, csr, E, lo, hi);
    }
    k_agg2<<<(n + 15) / 16, BS, 0, stream>>>(xbu, ptr, csr, aggb, n);
    k_gemm_mfma<<<512, BS, 0, stream>>>(aggb, xbu, W1l, b1, W1r, W2l, W2r,
                                        sarr, tarr, n, ntiles);
    k_final<<<nbN, BS, 0, stream>>>(ptr, csr, sarr, tarr, b2, out, n);
}

// Round 5
// 214.754 us; speedup vs baseline: 2.1423x; 1.4832x over previous
//
#include <hip/hip_runtime.h>

#define BS 256
#define THR 1024
#define NBLK 128          // blocks for pair/hist/scatter passes
#define BSH 4             // 16 nodes per coarse bucket

typedef __attribute__((ext_vector_type(8))) short bf16x8;
typedef __attribute__((ext_vector_type(4))) float f32x4;

__device__ inline unsigned bfpack2(float a, float b) {
    unsigned ua = __float_as_uint(a), ub = __float_as_uint(b);
    ua = (ua + 0x7fffu + ((ua >> 16) & 1u)) >> 16;
    ub = (ub + 0x7fffu + ((ub >> 16) & 1u)) >> 16;
    return ua | (ub << 16);
}
__device__ inline short bf16of(float a) {
    unsigned ua = __float_as_uint(a);
    ua = (ua + 0x7fffu + ((ua >> 16) & 1u)) >> 16;
    return (short)ua;
}
__device__ inline float lo16(unsigned u) { return __uint_as_float(u << 16); }
__device__ inline float hi16(unsigned u) { return __uint_as_float(u & 0xffff0000u); }

// ---------- dtype detection ----------
__global__ void k_detect(const int* __restrict__ idx, int* __restrict__ flag) {
    int l = threadIdx.x;
    int v = idx[2 * l + 1];
    unsigned long long b = __ballot(v != 0);
    if (l == 0) flag[0] = (b == 0ULL) ? 1 : 0;
}

// ---------- convert x to bf16 rows ----------
__global__ void k_xbf16(const float* __restrict__ x, unsigned* __restrict__ xb, int total8) {
    int i = blockIdx.x * BS + threadIdx.x;
    if (i >= total8) return;
    const float4 a = *(const float4*)(x + (size_t)i * 8);
    const float4 b = *(const float4*)(x + (size_t)i * 8 + 4);
    uint4 o;
    o.x = bfpack2(a.x, a.y); o.y = bfpack2(a.z, a.w);
    o.z = bfpack2(b.x, b.y); o.w = bfpack2(b.z, b.w);
    *(uint4*)(xb + (size_t)i * 4) = o;
}

// ---------- pass 1: idx -> packed pairs + per-block LDS coarse histogram ----------
__global__ __launch_bounds__(1024) void k_pairs_hist(const int* __restrict__ idx,
        const int* __restrict__ flag, int* __restrict__ pk,
        int* __restrict__ hcnt, int E, int NB) {
    extern __shared__ int hist[];
    int tid = threadIdx.x;
    for (int b = tid; b < NB; b += THR) hist[b] = 0;
    __syncthreads();
    int is64 = flag[0];
    int M = (E + 1) >> 1;
    for (int c = blockIdx.x * THR + tid; c < M; c += NBLK * THR) {
        int e0 = 2 * c;
        int s0, d0, s1 = 0, d1 = 0;
        bool two = (e0 + 1) < E;
        if (is64) {
            if (two) {
                int4 sv = *(const int4*)(idx + 4L * c);
                int4 dv = *(const int4*)(idx + 2L * E + 4L * c);
                s0 = sv.x; s1 = sv.z; d0 = dv.x; d1 = dv.z;
            } else {
                s0 = idx[2L * e0]; d0 = idx[2L * E + 2L * e0];
            }
        } else {
            if (two && !(E & 1)) {
                int2 sv = *(const int2*)(idx + 2L * c);
                int2 dv = *(const int2*)(idx + (long)E + 2L * c);
                s0 = sv.x; s1 = sv.y; d0 = dv.x; d1 = dv.y;
            } else {
                s0 = idx[e0]; d0 = idx[(long)E + e0];
                if (two) { s1 = idx[e0 + 1]; d1 = idx[(long)E + e0 + 1]; }
            }
        }
        if (two) {
            *(int4*)(pk + 4L * c) = make_int4(s0, d0, s1, d1);
            atomicAdd(&hist[d0 >> BSH], 1);
            atomicAdd(&hist[d1 >> BSH], 1);
        } else {
            *(int2*)(pk + 4L * c) = make_int2(s0, d0);
            atomicAdd(&hist[d0 >> BSH], 1);
        }
    }
    __syncthreads();
    int* hrow = hcnt + (long)blockIdx.x * NB;
    for (int b = tid; b < NB; b += THR) hrow[b] = hist[b];
}

// ---------- column-wise exclusive running sums over the NBLK private hists ----------
__global__ void k_colsum(int* __restrict__ hcnt, int* __restrict__ cnt, int NB) {
    int b = blockIdx.x * BS + threadIdx.x;
    if (b >= NB) return;
    int run = 0;
#pragma unroll 16
    for (int blk = 0; blk < NBLK; blk++) {
        int v = hcnt[(long)blk * NB + b];
        hcnt[(long)blk * NB + b] = run;
        run += v;
    }
    cnt[b] = run;
}

// ---------- exclusive scan over NB bucket counts (NB <= 8192) ----------
__global__ __launch_bounds__(1024) void k_scanNB(const int* __restrict__ cnt,
        int* __restrict__ cstart, int NB, int E) {
    __shared__ int sd[1024];
    int tid = threadIdx.x;
    int base = tid * 8;
    int v[8]; int tot = 0;
#pragma unroll
    for (int j = 0; j < 8; j++) {
        v[j] = (base + j < NB) ? cnt[base + j] : 0;
        tot += v[j];
    }
    sd[tid] = tot;
    __syncthreads();
    for (int off = 1; off < 1024; off <<= 1) {
        int x = (tid >= off) ? sd[tid - off] : 0;
        __syncthreads();
        sd[tid] += x;
        __syncthreads();
    }
    int run = sd[tid] - tot;
#pragma unroll
    for (int j = 0; j < 8; j++) {
        if (base + j < NB) cstart[base + j] = run;
        run += v[j];
    }
    if (tid == 0) cstart[NB] = E;
}

// ---------- pass 2: scatter pairs into bucket-grouped pk2, atomic-free (LDS cursors) ----------
__global__ __launch_bounds__(1024) void k_scatter2(const int* __restrict__ pk,
        const int* __restrict__ hcnt, const int* __restrict__ cstart,
        int* __restrict__ pk2, int E, int NB) {
    extern __shared__ int cur[];
    int tid = threadIdx.x;
    const int* hrow = hcnt + (long)blockIdx.x * NB;
    for (int b = tid; b < NB; b += THR) cur[b] = cstart[b] + hrow[b];
    __syncthreads();
    int M = (E + 1) >> 1;
    for (int c = blockIdx.x * THR + tid; c < M; c += NBLK * THR) {
        int e0 = 2 * c;
        if (e0 + 1 < E) {
            int4 p = *(const int4*)(pk + 4L * c);
            int pos0 = atomicAdd(&cur[p.y >> BSH], 1);
            *(int2*)(pk2 + 2L * pos0) = make_int2(p.x, p.y);
            int pos1 = atomicAdd(&cur[p.w >> BSH], 1);
            *(int2*)(pk2 + 2L * pos1) = make_int2(p.z, p.w);
        } else {
            int2 p = *(const int2*)(pk + 4L * c);
            int pos0 = atomicAdd(&cur[p.y >> BSH], 1);
            *(int2*)(pk2 + 2L * pos0) = make_int2(p.x, p.y);
        }
    }
}

// ---------- pass 3: per-bucket node grouping -> ptr + csr ----------
__global__ __launch_bounds__(256) void k_build(const int* __restrict__ pk2,
        const int* __restrict__ cstart, int* __restrict__ ptr,
        int* __restrict__ csr, int n, int E) {
    __shared__ int h16[16], base16[16], cur16[16];
    int b = blockIdx.x;
    int tid = threadIdx.x;
    if (tid < 16) { h16[tid] = 0; cur16[tid] = 0; }
    __syncthreads();
    int ebeg = cstart[b], eend = cstart[b + 1];
    for (int i = ebeg + tid; i < eend; i += 256) {
        int d = pk2[2L * i + 1];
        atomicAdd(&h16[d & 15], 1);
    }
    __syncthreads();
    if (tid == 0) {
        int run = 0;
#pragma unroll
        for (int j = 0; j < 16; j++) { base16[j] = run; run += h16[j]; }
    }
    __syncthreads();
    if (tid < 16) {
        int node = b * 16 + tid;
        if (node < n) ptr[node] = ebeg + base16[tid];
    }
    if (b == 0 && tid == 0) ptr[n] = E;
    for (int i = ebeg + tid; i < eend; i += 256) {
        int2 p = *(const int2*)(pk2 + 2L * i);
        int ln = p.y & 15;
        int pos = base16[ln] + atomicAdd(&cur16[ln], 1);
        csr[ebeg + pos] = p.x;
    }
}

// ---------- layer-1 mean aggregation over bf16 rows, 4-deep MLP ----------
__global__ __launch_bounds__(256) void k_agg2(const unsigned short* __restrict__ xb,
                                              const int* __restrict__ ptr,
                                              const int* __restrict__ csr,
                                              unsigned short* __restrict__ aggb, int n) {
    int node = blockIdx.x * 16 + (threadIdx.x >> 4);
    int lane = threadIdx.x & 15;
    if (node >= n) return;
    int p0 = ptr[node], p1 = ptr[node + 1];
    float f0 = 0.f, f1 = 0.f, f2 = 0.f, f3 = 0.f;
    const unsigned short* base = xb + lane * 4;
    int e = p0;
    for (; e + 4 <= p1; e += 4) {
        int j0 = csr[e], j1 = csr[e + 1], j2 = csr[e + 2], j3 = csr[e + 3];
        uint2 v0 = *(const uint2*)(base + (size_t)j0 * 64);
        uint2 v1 = *(const uint2*)(base + (size_t)j1 * 64);
        uint2 v2 = *(const uint2*)(base + (size_t)j2 * 64);
        uint2 v3 = *(const uint2*)(base + (size_t)j3 * 64);
        f0 += lo16(v0.x) + lo16(v1.x) + lo16(v2.x) + lo16(v3.x);
        f1 += hi16(v0.x) + hi16(v1.x) + hi16(v2.x) + hi16(v3.x);
        f2 += lo16(v0.y) + lo16(v1.y) + lo16(v2.y) + lo16(v3.y);
        f3 += hi16(v0.y) + hi16(v1.y) + hi16(v2.y) + hi16(v3.y);
    }
    for (; e < p1; e++) {
        int j = csr[e];
        uint2 v = *(const uint2*)(base + (size_t)j * 64);
        f0 += lo16(v.x); f1 += hi16(v.x); f2 += lo16(v.y); f3 += hi16(v.y);
    }
    int d = p1 - p0; if (d < 1) d = 1;
    float inv = 1.0f / (float)d;
    uint2 o;
    o.x = bfpack2(f0 * inv, f1 * inv);
    o.y = bfpack2(f2 * inv, f3 * inv);
    *(uint2*)(aggb + (size_t)node * 64 + lane * 4) = o;
}

// ---------- MFMA layer-1 GEMM + relu + layer-2 projections ----------
__global__ __launch_bounds__(256) void k_gemm_mfma(
        const unsigned short* __restrict__ aggb, const unsigned short* __restrict__ xb,
        const float* __restrict__ W1l, const float* __restrict__ b1,
        const float* __restrict__ W1r, const float* __restrict__ W2l,
        const float* __restrict__ W2r,
        float* __restrict__ sarr, float* __restrict__ tarr, int n, int ntiles) {
    int lane = threadIdx.x & 63;
    int nloc = lane & 15;
    int quad = lane >> 4;
    int wave = blockIdx.x * 4 + (threadIdx.x >> 6);
    int nwaves = gridDim.x * 4;

    bf16x8 bfrag[2][4][2];
#pragma unroll
    for (int t = 0; t < 4; t++)
#pragma unroll
        for (int s = 0; s < 2; s++)
#pragma unroll
            for (int i = 0; i < 8; i++) {
                int k = s * 32 + quad * 8 + i;
                int j = t * 16 + nloc;
                bfrag[0][t][s][i] = bf16of(W1l[k * 64 + j]);
                bfrag[1][t][s][i] = bf16of(W1r[k * 64 + j]);
            }
    float b1v[4], w2lv[4], w2rv[4];
#pragma unroll
    for (int t = 0; t < 4; t++) {
        b1v[t] = b1[t * 16 + nloc];
        w2lv[t] = W2l[t * 16 + nloc];
        w2rv[t] = W2r[t * 16 + nloc];
    }

    for (int tile = wave; tile < ntiles; tile += nwaves) {
        int node = tile * 16 + nloc;
        int nc = node < n ? node : (n - 1);
        const unsigned short* ar = aggb + (size_t)nc * 64;
        const unsigned short* xr = xb + (size_t)nc * 64;
        bf16x8 aA0 = *(const bf16x8*)(ar + quad * 8);
        bf16x8 aA1 = *(const bf16x8*)(ar + 32 + quad * 8);
        bf16x8 aX0 = *(const bf16x8*)(xr + quad * 8);
        bf16x8 aX1 = *(const bf16x8*)(xr + 32 + quad * 8);
        f32x4 acc[4];
#pragma unroll
        for (int t = 0; t < 4; t++) {
            acc[t] = (f32x4){0.f, 0.f, 0.f, 0.f};
            acc[t] = __builtin_amdgcn_mfma_f32_16x16x32_bf16(aA0, bfrag[0][t][0], acc[t], 0, 0, 0);
            acc[t] = __builtin_amdgcn_mfma_f32_16x16x32_bf16(aA1, bfrag[0][t][1], acc[t], 0, 0, 0);
            acc[t] = __builtin_amdgcn_mfma_f32_16x16x32_bf16(aX0, bfrag[1][t][0], acc[t], 0, 0, 0);
            acc[t] = __builtin_amdgcn_mfma_f32_16x16x32_bf16(aX1, bfrag[1][t][1], acc[t], 0, 0, 0);
        }
        float sr[4] = {0.f, 0.f, 0.f, 0.f};
        float tr[4] = {0.f, 0.f, 0.f, 0.f};
#pragma unroll
        for (int t = 0; t < 4; t++)
#pragma unroll
            for (int r = 0; r < 4; r++) {
                float h = acc[t][r] + b1v[t];
                h = fmaxf(h, 0.f);
                sr[r] = fmaf(h, w2lv[t], sr[r]);
                tr[r] = fmaf(h, w2rv[t], tr[r]);
            }
#pragma unroll
        for (int m = 1; m < 16; m <<= 1) {
#pragma unroll
            for (int r = 0; r < 4; r++) {
                sr[r] += __shfl_xor(sr[r], m);
                tr[r] += __shfl_xor(tr[r], m);
            }
        }
        if (nloc == 0) {
#pragma unroll
            for (int r = 0; r < 4; r++) {
                int nd = tile * 16 + quad * 4 + r;
                if (nd < n) { sarr[nd] = sr[r]; tarr[nd] = tr[r]; }
            }
        }
    }
}

// ---------- layer-2 mean aggregation of scalar s + output ----------
__global__ void k_final(const int* __restrict__ ptr, const int* __restrict__ csr,
                        const float* __restrict__ sarr, const float* __restrict__ tarr,
                        const float* __restrict__ b2, float* __restrict__ out, int n) {
    int i = blockIdx.x * BS + threadIdx.x;
    if (i >= n) return;
    int p0 = ptr[i], p1 = ptr[i + 1];
    float a = 0.f;
    int e = p0;
    for (; e + 4 <= p1; e += 4) {
        int j0 = csr[e], j1 = csr[e + 1], j2 = csr[e + 2], j3 = csr[e + 3];
        a += sarr[j0] + sarr[j1] + sarr[j2] + sarr[j3];
    }
    for (; e < p1; e++) a += sarr[csr[e]];
    int d = p1 - p0; if (d < 1) d = 1;
    out[i] = a / (float)d + b2[0] + tarr[i];
}

extern "C" void kernel_launch(void* const* d_in, const int* in_sizes, int n_in,
                              void* d_out, int out_size, void* d_ws, size_t ws_size,
                              hipStream_t stream) {
    const float* x   = (const float*)d_in[0];
    const int*   idx = (const int*)d_in[1];
    const float* W1l = (const float*)d_in[2];
    const float* b1  = (const float*)d_in[3];
    const float* W1r = (const float*)d_in[4];
    const float* W2l = (const float*)d_in[5];
    const float* b2  = (const float*)d_in[6];
    const float* W2r = (const float*)d_in[7];
    float* out = (float*)d_out;

    const int n = in_sizes[0] / 64;     // 100000
    const int E = in_sizes[1] / 2;      // 1600000
    const int NB = (n + 15) >> BSH;     // coarse buckets (16 nodes each)

    char* ws = (char*)d_ws;
    size_t off = 0;
    auto carve = [&](size_t bytes) {
        void* p = ws + off;
        off = (off + bytes + 255) & ~(size_t)255;
        return p;
    };
    int*   flag   = (int*)  carve(4);
    int*   ptr    = (int*)  carve((size_t)(n + 1) * 4);
    int*   csr    = (int*)  carve((size_t)E * 4);
    float* sarr   = (float*)carve((size_t)n * 4);
    float* tarr   = (float*)carve((size_t)n * 4);
    int*   cnt    = (int*)  carve((size_t)NB * 4);
    int*   cstart = (int*)  carve((size_t)(NB + 1) * 4);
    int*   hcnt   = (int*)  carve((size_t)NBLK * NB * 4);
    // union A: pk (pairs, E*8) alias aggb (n*64*2) — disjoint lifetimes
    size_t szA = (size_t)E * 8 > (size_t)n * 128 ? (size_t)E * 8 : (size_t)n * 128;
    char*  uniA = (char*)carve(szA);
    int*   pk   = (int*)uniA;
    unsigned short* aggb = (unsigned short*)uniA;
    // union B: pk2 (E*8) alias xb (n*64*2)
    size_t szB = szA;
    char*  uniB = (char*)carve(szB);
    int*   pk2  = (int*)uniB;
    unsigned short* xbu = (unsigned short*)uniB;
    (void)ws_size; (void)n_in; (void)out_size;

    const int nbN = (n + BS - 1) / BS;
    const int total8 = n * 64 / 8;
    const int ntiles = (n + 15) / 16;
    const size_t ldsNB = (size_t)NB * 4;

    k_detect<<<1, 64, 0, stream>>>(idx, flag);
    k_pairs_hist<<<NBLK, THR, ldsNB, stream>>>(idx, flag, pk, hcnt, E, NB);
    k_colsum<<<(NB + BS - 1) / BS, BS, 0, stream>>>(hcnt, cnt, NB);
    k_scanNB<<<1, 1024, 0, stream>>>(cnt, cstart, NB, E);
    k_scatter2<<<NBLK, THR, ldsNB, stream>>>(pk, hcnt, cstart, pk2, E, NB);
    k_build<<<NB, BS, 0, stream>>>(pk2, cstart, ptr, csr, n, E);
    k_xbf16<<<(total8 + BS - 1) / BS, BS, 0, stream>>>(x, (unsigned*)xbu, total8);
    k_agg2<<<(n + 15) / 16, BS, 0, stream>>>(xbu, ptr, csr, aggb, n);
    k_gemm_mfma<<<512, BS, 0, stream>>>(aggb, xbu, W1l, b1, W1r, W2l, W2r,
                                        sarr, tarr, n, ntiles);
    k_final<<<nbN, BS, 0, stream>>>(ptr, csr, sarr, tarr, b2, out, n);
}